// Round 11
// baseline (3571.741 us; speedup 1.0000x reference)
//
#include <hip/hip_runtime.h>

#define EMBED   300
#define HIDDEN  256
#define SEQ     256
#define NG      1024          // 4*HIDDEN
#define NL1     16
#define NL2     16
#define NBLK    96            // 16 L1 + 16 L2 + 64 helpers
#define CAP     (1 << 14)     // poll failsafe cap

typedef __attribute__((ext_vector_type(8))) short  short8;   // 8 bf16
typedef __attribute__((ext_vector_type(4))) float  f32x4;
typedef unsigned long long ull;

__device__ inline unsigned f2bf(float f) {
    unsigned u = __builtin_bit_cast(unsigned, f);
    return (u + 0x7FFFu + ((u >> 16) & 1u)) >> 16;   // RNE, low 16 bits
}
__device__ inline float bf2f(unsigned short h) {
    unsigned u = (unsigned)h << 16;
    return __builtin_bit_cast(float, u);
}
__device__ inline float sigm(float x)  { return 1.0f / (1.0f + __expf(-x)); }
__device__ inline float tanh_(float x) { return 2.0f / (1.0f + __expf(-2.0f * x)) - 1.0f; }
__device__ inline int swzb(int c, int base) { return base ^ (((c >> 1) & 3) << 4); }

// relaxed agent-scope (LLC-coherent, per-XCD-L2 bypass) — proven r3..r9
__device__ inline unsigned ld32a(const unsigned* p) {
    return __hip_atomic_load(p, __ATOMIC_RELAXED, __HIP_MEMORY_SCOPE_AGENT);
}
__device__ inline void st32a(unsigned* p, unsigned v) {
    __hip_atomic_store(p, v, __ATOMIC_RELAXED, __HIP_MEMORY_SCOPE_AGENT);
}
__device__ inline ull ld64a(const ull* p) {
    return __hip_atomic_load(p, __ATOMIC_RELAXED, __HIP_MEMORY_SCOPE_AGENT);
}
__device__ inline float ldf32a(const float* p) {
    return __builtin_bit_cast(float, ld32a((const unsigned*)p));
}
__device__ inline void stf32a(float* p, float v) {
    st32a((unsigned*)p, __builtin_bit_cast(unsigned, v));
}

#define MFMA(a, b, c) __builtin_amdgcn_mfma_f32_16x16x32_bf16((a), (b), (c), 0, 0, 0)
#define TAGMASK 0x0000FFFF0000FFFFULL

// flags (u32 idx, packed): f1[i]=flags[i] (i<16): L1 i finished READS for epoch f1-1
//   f2[i]=flags[16+i]: L2 i finished READS for step f2-1
//   fh[p][s]=flags[32+p*32+s] (p<2): helper stored gx1 tile t -> t+1
// h1t/h2t: tagged rings [4][64][256] u32, word = (bf16(h)<<16) | ((e+1)&0xFFFF);
//   memset-0 => slot content "epoch -1" (tag 0, h=0).
__global__ __launch_bounds__(256, 1) void lstm_v11(
    const int*   __restrict__ xin,
    const float* __restrict__ emb,
    const float* __restrict__ W0, const float* __restrict__ b0,
    const float* __restrict__ W1, const float* __restrict__ b1,
    unsigned*       __restrict__ flags,
    unsigned*       __restrict__ h1t,
    unsigned*       __restrict__ h2t,
    float*          __restrict__ ring1,   // [4][64][1024] f32 (b0 folded)
    float*          __restrict__ out)     // [64][256] f32
{
    extern __shared__ char lds[];
    int* okw = (int*)(lds + 65536);
    const int tid = threadIdx.x, bid = blockIdx.x;
    const int w = tid >> 6, lane = tid & 63, l15 = lane & 15, q = lane >> 4;
    const int bbase = w * 16, arow = bbase + l15;

    auto blockOK = [&](bool ok) -> bool {
        if (lane == 0) okw[w] = ok ? 1 : 0;
        __syncthreads();
        bool r = okw[0] && okw[1] && okw[2] && okw[3];
        __syncthreads();
        return r;
    };

    // =====================================================================
    if (bid < NL1) {                       // ---- L1 recurrence (16-unit stripes) ----
        const int u0 = bid * 16;
        short8 bfragR[8][4];
        #pragma unroll
        for (int s = 0; s < 8; ++s)
            #pragma unroll
            for (int nt = 0; nt < 4; ++nt)
                #pragma unroll
                for (int e2 = 0; e2 < 8; ++e2) {
                    int k = EMBED + s * 32 + q * 8 + e2;
                    bfragR[s][nt][e2] = (short)f2bf(W0[(long)k * NG + nt * 256 + u0 + l15]);
                }

        {   // preloop: gx[0] present (parity-0 helpers)
            bool ok = true;
            if (w == 0) {
                int n = 0;
                for (;;) {
                    bool c = (lane < 32) ? (ld32a(flags + 32 + lane) >= 1u) : true;
                    if (__all(c)) break;
                    if (++n > CAP) { if (lane == 0) stf32a(out, 52000.f); ok = false; break; }
                }
            }
            if (!blockOK(ok)) return;
        }
        f32x4 gn[4];
        #pragma unroll
        for (int nt = 0; nt < 4; ++nt)
            #pragma unroll
            for (int rr = 0; rr < 4; ++rr)
                gn[nt][rr] = ldf32a(ring1 + (size_t)(bbase + q * 4 + rr) * NG + nt * 256 + u0 + l15);

        float c4[4] = {0.f, 0.f, 0.f, 0.f};
        for (int e = 0; e <= 255; ++e) {
            // ---- tagged poll-read h1[e-1] (tag = e) : poll IS the data read ----
            short8 a1[8];
            bool ok = true;
            {
                const unsigned tag = (unsigned)e & 0xFFFFu;
                const ull tp = (ull)tag | ((ull)tag << 32);
                const ull* rb = (const ull*)(h1t + (size_t)((e - 1) & 3) * 16384 + arow * 256);
                ull v[8][4];
                int n = 0;
                for (;;) {
                    bool o = true;
                    #pragma unroll
                    for (int s = 0; s < 8; ++s)
                        #pragma unroll
                        for (int j = 0; j < 4; ++j)
                            v[s][j] = ld64a(rb + s * 16 + q * 4 + j);
                    #pragma unroll
                    for (int s = 0; s < 8; ++s)
                        #pragma unroll
                        for (int j = 0; j < 4; ++j)
                            o = o && (((v[s][j] ^ tp) & TAGMASK) == 0ULL);
                    if (__all(o)) break;
                    if (++n > CAP) { if (lane == 0) stf32a(out, 51000.f + (float)e); ok = false; break; }
                }
                #pragma unroll
                for (int s = 0; s < 8; ++s)
                    #pragma unroll
                    for (int j = 0; j < 4; ++j) {
                        a1[s][2 * j]     = (short)(unsigned)(v[s][j] >> 16);
                        a1[s][2 * j + 1] = (short)(unsigned)(v[s][j] >> 48);
                    }
            }
            if (!blockOK(ok)) break;
            if (tid == 0) st32a(flags + bid, (unsigned)(e + 1));   // f1: reads for e done

            f32x4 acc[4] = {gn[0], gn[1], gn[2], gn[3]};
            #pragma unroll
            for (int s = 0; s < 8; ++s)
                #pragma unroll
                for (int nt = 0; nt < 4; ++nt)
                    acc[nt] = MFMA(a1[s], bfragR[s][nt], acc[nt]);

            // cell update + tagged publish (no drain, no flag)
            unsigned* hw = h1t + (size_t)(e & 3) * 16384;
            const unsigned tw = (unsigned)(e + 1) & 0xFFFFu;
            #pragma unroll
            for (int rr = 0; rr < 4; ++rr) {
                int b = bbase + q * 4 + rr;
                float iv = sigm(acc[0][rr]);
                float jv = tanh_(acc[1][rr]);
                float fv = sigm(acc[2][rr] + 1.0f);
                float ov = sigm(acc[3][rr]);
                float cn = c4[rr] * fv + iv * jv;
                c4[rr] = cn;
                unsigned hb = f2bf(tanh_(cn) * ov);
                st32a(hw + b * 256 + u0 + l15, (hb << 16) | tw);
            }

            // ---- slack: backpressure (2-epoch margin) + gx[e+1] gate + prefetch ----
            if (e <= 254) {
                bool ok2 = true;
                if (w == 0) {
                    int n = 0;
                    for (;;) {
                        bool c = true;
                        if (lane < 16)      { if (e >= 2) c = ld32a(flags + lane) >= (unsigned)(e - 1); }
                        else if (lane < 32) { if (e >= 3) c = ld32a(flags + lane) >= (unsigned)(e - 2); }
                        else                { c = ld32a(flags + 32 + ((e + 1) & 1) * 32 + (lane - 32)) >= (unsigned)(e + 2); }
                        if (__all(c)) break;
                        if (++n > CAP) { if (lane == 0) stf32a(out, 53000.f + (float)e); ok2 = false; break; }
                    }
                }
                if (!blockOK(ok2)) break;
                const float* g1 = ring1 + (size_t)((e + 1) & 3) * (64 * NG);
                #pragma unroll
                for (int nt = 0; nt < 4; ++nt)
                    #pragma unroll
                    for (int rr = 0; rr < 4; ++rr)
                        gn[nt][rr] = ldf32a(g1 + (size_t)(bbase + q * 4 + rr) * NG + nt * 256 + u0 + l15);
            }
        }

    // =====================================================================
    } else if (bid < NL1 + NL2) {          // ---- L2: x-part + rec, both W in LDS ----
        const int idx = bid - NL1, u0 = idx * 16, u = u0 + l15;
        float biasx[4];
        #pragma unroll
        for (int nt = 0; nt < 4; ++nt) biasx[nt] = b1[nt * 256 + u0 + l15];
        // stage W1 rows 0..511 (x rows 0..255 -> regions 0..7; rec rows 256..511 -> 8..15)
        for (int i2 = tid; i2 < 16 * 64 * 32; i2 += 256) {
            int k = i2 >> 6, c = i2 & 63;
            int col = (c >> 4) * 256 + u0 + (c & 15);
            int s = k >> 5, kk = k & 31;
            *(unsigned short*)(lds + s * 4096 + swzb(c, c * 64 + kk * 2)) =
                (unsigned short)f2bf(W1[(long)k * NG + col]);
        }
        __syncthreads();

        float c4[4] = {0.f, 0.f, 0.f, 0.f};
        for (int t = 0; t <= 255; ++t) {
            // ---- combined tagged poll-read: h1[t] (tag t+1) + h2[t-1] (tag t) ----
            short8 a1[8], a2[8];
            bool ok = true;
            {
                const unsigned tg1 = (unsigned)(t + 1) & 0xFFFFu;
                const unsigned tg2 = (unsigned)t & 0xFFFFu;
                const ull tp1 = (ull)tg1 | ((ull)tg1 << 32);
                const ull tp2 = (ull)tg2 | ((ull)tg2 << 32);
                const ull* r1 = (const ull*)(h1t + (size_t)(t & 3) * 16384 + arow * 256);
                const ull* r2 = (const ull*)(h2t + (size_t)((t - 1) & 3) * 16384 + arow * 256);
                ull v1[8][4], v2[8][4];
                int n = 0;
                for (;;) {
                    bool o = true;
                    #pragma unroll
                    for (int s = 0; s < 8; ++s)
                        #pragma unroll
                        for (int j = 0; j < 4; ++j) {
                            v1[s][j] = ld64a(r1 + s * 16 + q * 4 + j);
                            v2[s][j] = ld64a(r2 + s * 16 + q * 4 + j);
                        }
                    #pragma unroll
                    for (int s = 0; s < 8; ++s)
                        #pragma unroll
                        for (int j = 0; j < 4; ++j)
                            o = o && (((v1[s][j] ^ tp1) & TAGMASK) == 0ULL)
                                  && (((v2[s][j] ^ tp2) & TAGMASK) == 0ULL);
                    if (__all(o)) break;
                    if (++n > CAP) { if (lane == 0) stf32a(out, 54000.f + (float)t); ok = false; break; }
                }
                #pragma unroll
                for (int s = 0; s < 8; ++s)
                    #pragma unroll
                    for (int j = 0; j < 4; ++j) {
                        a1[s][2 * j]     = (short)(unsigned)(v1[s][j] >> 16);
                        a1[s][2 * j + 1] = (short)(unsigned)(v1[s][j] >> 48);
                        a2[s][2 * j]     = (short)(unsigned)(v2[s][j] >> 16);
                        a2[s][2 * j + 1] = (short)(unsigned)(v2[s][j] >> 48);
                    }
            }
            if (!blockOK(ok)) break;
            if (tid == 0) st32a(flags + 16 + idx, (unsigned)(t + 1));   // f2: reads for t done

            f32x4 acc[4];
            #pragma unroll
            for (int nt = 0; nt < 4; ++nt)
                acc[nt] = (f32x4){biasx[nt], biasx[nt], biasx[nt], biasx[nt]};
            #pragma unroll
            for (int s = 0; s < 8; ++s)
                #pragma unroll
                for (int nt = 0; nt < 4; ++nt) {
                    int c = nt * 16 + l15;
                    short8 bx = *(const short8*)(lds + s * 4096 + swzb(c, c * 64 + q * 16));
                    acc[nt] = MFMA(a1[s], bx, acc[nt]);
                }
            #pragma unroll
            for (int s = 0; s < 8; ++s)
                #pragma unroll
                for (int nt = 0; nt < 4; ++nt) {
                    int c = nt * 16 + l15;
                    short8 br = *(const short8*)(lds + (8 + s) * 4096 + swzb(c, c * 64 + q * 16));
                    acc[nt] = MFMA(a2[s], br, acc[nt]);
                }

            unsigned* hw = h2t + (size_t)(t & 3) * 16384;
            const unsigned tw = (unsigned)(t + 1) & 0xFFFFu;
            #pragma unroll
            for (int rr = 0; rr < 4; ++rr) {
                int b = bbase + q * 4 + rr;
                float iv = sigm(acc[0][rr]);
                float jv = tanh_(acc[1][rr]);
                float fv = sigm(acc[2][rr] + 1.0f);
                float ov = sigm(acc[3][rr]);
                float cn = c4[rr] * fv + iv * jv;
                c4[rr] = cn;
                float hn = tanh_(cn) * ov;
                if (t == 255) out[b * HIDDEN + u] = hn;
                else st32a(hw + b * 256 + u0 + l15, (f2bf(hn) << 16) | tw);
            }
            if (t == 255) break;

            // slack: peer-consumption backpressure for writing h2[t+1]
            if (t >= 2 && t <= 253) {
                bool ok2 = true;
                if (w == 0) {
                    int n = 0;
                    for (;;) {
                        bool c = (lane < 16) ? (ld32a(flags + 16 + lane) >= (unsigned)(t - 1)) : true;
                        if (__all(c)) break;
                        if (++n > CAP) { if (lane == 0) stf32a(out, 56000.f + (float)t); ok2 = false; break; }
                    }
                }
                if (!blockOK(ok2)) break;
            }
        }

    // =====================================================================
    } else {                               // ---- gx1 helpers (parity x 32 slices) ----
        const int hidx = bid - NL1 - NL2;  // 0..63
        const int par = hidx & 1, slice = hidx >> 1, hc0 = slice * 32;
        float biasH[2];
        #pragma unroll
        for (int gi = 0; gi < 2; ++gi) biasH[gi] = b0[hc0 + gi * 16 + l15];
        for (int i2 = tid; i2 < 20 * 32 * 32; i2 += 256) {   // W0 x-part hi+lo residual
            int k = i2 >> 5, c = i2 & 31;
            int s = k >> 5, kk = k & 31;
            int row = (s >= 10) ? (k - 320) : k;
            float v = W0[(long)row * NG + hc0 + c];
            unsigned hv = f2bf(v);
            if (s >= 10) hv = f2bf(v - bf2f((unsigned short)hv));
            *(unsigned short*)(lds + s * 2048 + swzb(c, c * 64 + kk * 2)) = (unsigned short)hv;
        }
        __syncthreads();

        for (int t = par; t <= 255; t += 2) {
            int xid = xin[arow * SEQ + t];
            const float* erow = emb + (long)xid * EMBED;
            short8 ac[10];
            #pragma unroll
            for (int s = 0; s < 10; ++s) {
                int kb = s * 32 + q * 8;
                #pragma unroll
                for (int hh = 0; hh < 2; ++hh) {
                    int k4 = kb + hh * 4;
                    if (k4 < EMBED) {
                        f32x4 v = *(const f32x4*)(erow + k4);
                        #pragma unroll
                        for (int e2 = 0; e2 < 4; ++e2) ac[s][hh * 4 + e2] = (short)f2bf(v[e2]);
                    } else {
                        #pragma unroll
                        for (int e2 = 0; e2 < 4; ++e2) ac[s][hh * 4 + e2] = 0;
                    }
                }
            }
            f32x4 accg[2];
            #pragma unroll
            for (int gi = 0; gi < 2; ++gi)
                accg[gi] = (f32x4){biasH[gi], biasH[gi], biasH[gi], biasH[gi]};
            #pragma unroll
            for (int s = 0; s < 20; ++s) {
                short8 a = ac[(s < 10) ? s : s - 10];
                #pragma unroll
                for (int gi = 0; gi < 2; ++gi) {
                    int c = gi * 16 + l15;
                    short8 b = *(const short8*)(lds + s * 2048 + swzb(c, c * 64 + q * 16));
                    accg[gi] = MFMA(a, b, accg[gi]);
                }
            }
            // slot gate: all L1 f1 >= t-2  (epoch t-4 fully done -> gx[t-4] consumed)
            if (t >= 4) {
                bool ok = true;
                if (w == 0) {
                    int n = 0;
                    for (;;) {
                        bool c = (lane < 16) ? (ld32a(flags + lane) >= (unsigned)(t - 2)) : true;
                        if (__all(c)) break;
                        if (++n > CAP) { if (lane == 0) stf32a(out, 55000.f + (float)t); ok = false; break; }
                    }
                }
                if (!blockOK(ok)) break;
            }
            float* dst = ring1 + (size_t)(t & 3) * (64 * NG);
            #pragma unroll
            for (int gi = 0; gi < 2; ++gi)
                #pragma unroll
                for (int rr = 0; rr < 4; ++rr)
                    stf32a(dst + (size_t)(bbase + q * 4 + rr) * NG + hc0 + gi * 16 + l15, accg[gi][rr]);
            asm volatile("s_waitcnt vmcnt(0)" ::: "memory");
            __syncthreads();
            if (tid == 0) st32a(flags + 32 + par * 32 + slice, (unsigned)(t + 1));
        }
    }
}

__global__ void ws_too_small_sentinel(float* out, int n) {
    int i = blockIdx.x * 256 + threadIdx.x;
    if (i < n) out[i] = 31337.0f;
}

extern "C" void kernel_launch(void* const* d_in, const int* in_sizes, int n_in,
                              void* d_out, int out_size, void* d_ws, size_t ws_size,
                              hipStream_t stream)
{
    const int*   xin = (const int*)d_in[0];
    const float* emb = (const float*)d_in[1];
    const float* W0  = (const float*)d_in[2];
    const float* b0  = (const float*)d_in[3];
    const float* W1  = (const float*)d_in[4];
    const float* b1  = (const float*)d_in[5];
    float* out = (float*)d_out;

    const size_t OFF_FLAGS = 0;                            // 4 KB
    const size_t OFF_H1    = 4096;                         // 256 KB tagged ring
    const size_t OFF_H2    = OFF_H1 + 262144;              // 256 KB tagged ring
    const size_t OFF_RING1 = OFF_H2 + 262144;              // 1 MB
    const size_t NEED      = OFF_RING1 + (size_t)4 * 64 * NG * 4;   // 1,576,960 B (< proven 1,589,248)

    if (ws_size < NEED) {   // diagnostic: absmax ~31337 => ws too small
        ws_too_small_sentinel<<<(out_size + 255) / 256, 256, 0, stream>>>(out, out_size);
        return;
    }

    char* ws = (char*)d_ws;
    unsigned* flags = (unsigned*)(ws + OFF_FLAGS);
    unsigned* h1t   = (unsigned*)(ws + OFF_H1);
    unsigned* h2t   = (unsigned*)(ws + OFF_H2);
    float*    ring1 = (float*)(ws + OFF_RING1);

    // zero flags + both tagged rings (clears cross-replay stale tags; tag 0 == "h[-1]=0")
    hipMemsetAsync(ws, 0, OFF_RING1, stream);
    lstm_v11<<<dim3(NBLK), dim3(256), 66560, stream>>>(
        xin, emb, W0, b0, W1, b1, flags, h1t, h2t, ring1, out);
}